// Round 3
// baseline (226.017 us; speedup 1.0000x reference)
//
#include <hip/hip_runtime.h>
#include <math.h>

#define HID    64
#define MSTEPS 60
#define NPTS   32
#define RPTSC  128
#define BTOT   (RPTSC*NPTS)    // 4096 paths
#define NSIM   (2*BTOT)        // 8192 path-branches
#define NWAVE  (NSIM/2)        // 4096 waves, 2 path-branches per wave
#define NBLK   (NWAVE/4)       // 1024 blocks

// hard-coded model constants (match reference, fp32 semantics)
#define C_DT     0.025f
#define C_SQDT   0.15811388300841897f   // sqrt(0.025)
#define C_ALPHA  0.8f
#define C_RHO    0.3f
#define C_SQ1MR2 0.9539392014169456f    // sqrt(1-0.09)
#define C_KAPPA  1.2f
#define C_R      0.02f
#define C_SIGMA  0.2f
#define C_SIGY   0.3f
#define C_LBW    1e-3f
#define C_LOGLBW -6.907755279f          // log(1e-3)
#define C_2L2E   2.8853900817779268f    // 2*log2(e): tanh(x)=1-2/(2^(x*2L2E)+1)

// per-wave LDS layout:
//   [0,2304)      A-buffer: 16 rows x 144 B (64 f16 + 16 B pad)
//   [2304,4352)   DVf: f32x4 per (unit,path): u*32 + p*16  (a0,aW,aY,aWW)
//   [4352,4864)   DAf: f32 per (unit,path):   u*8  + p*4   (aWY)
#define WAVE_LDS 4864
#define A_ROW    144
#define OFF_DV   2304
#define OFF_DA   4352

typedef _Float16 half8 __attribute__((ext_vector_type(8)));
typedef float    f32x4 __attribute__((ext_vector_type(4)));
typedef _Float16 h2    __attribute__((ext_vector_type(2)));

__device__ __forceinline__ float rlanef(float v, int l) {
    return __int_as_float(__builtin_amdgcn_readlane(__float_as_int(v), l));
}
// static-pattern lane crossbar within 32-lane groups (BitMode):
// src_lane = ((lane & and) | or) ^ xor ; offset = (xor<<10)|(or<<5)|and
template <int OFF>
__device__ __forceinline__ float swz(float v) {
    return __int_as_float(__builtin_amdgcn_ds_swizzle(__float_as_int(v), OFF));
}
__device__ __forceinline__ f32x4 MFMA(half8 a, half8 b, f32x4 c) {
    return __builtin_amdgcn_mfma_f32_16x16x32_f16(a, b, c, 0, 0, 0);
}
__device__ __forceinline__ h2 pk2(float a, float b) {
    return __builtin_bit_cast(h2, __builtin_amdgcn_cvt_pkrtz(a, b));
}
// tanh with argument pre-scaled by 2*log2(e): tanh = 1 - 2/(2^xs + 1)
__device__ __forceinline__ float tanh_fast(float xs) {
    return 1.0f - 2.0f * __builtin_amdgcn_rcpf(__builtin_amdgcn_exp2f(xs) + 1.0f);
}

// sim + fused projection (last block to finish does the reduction).
// sd[c*NSIM + branch], branch = simb*BTOT + pg; branch & 31 == eval point.
__global__ __launch_bounds__(256, 4) void sim_kernel(
    const float* __restrict__ noise,
    const float* __restrict__ w1, const float* __restrict__ b1,
    const float* __restrict__ w2, const float* __restrict__ b2,
    const float* __restrict__ w3, const float* __restrict__ b3,
    const float* __restrict__ Wp, const float* __restrict__ Yp,
    float* __restrict__ sd, unsigned int* __restrict__ cnt,
    float* __restrict__ out)
{
    __shared__ __align__(16) char smem[4 * WAVE_LDS];
    __shared__ int lastf;
    const int lane = threadIdx.x & 63;
    const int quad = lane >> 4;      // 0..3
    const int mrow = lane & 15;      // 0..15
    const int par  = lane >> 5;      // path half: lanes 0-31 path0, 32-63 path1
    char* wb = smem + (threadIdx.x >> 6) * WAVE_LDS;

    const int w = __builtin_amdgcn_readfirstlane(
        (int)((blockIdx.x * blockDim.x + threadIdx.x) >> 6));   // 0..4095
    const int simb = w >> 11;                 // antithetic branch (uniform per wave)
    const int pg   = 2*(w & 2047) + par;      // per-lane global path 0..4095
    const int i    = pg & (NPTS - 1);         // per-lane eval point

    // per-lane layer-1 weights (lane = hidden unit)
    const float cW  = w1[lane];
    const float cT  = w1[HID + lane];
    const float cYw = w1[2*HID + lane];
    const float b1k = b1[lane];
    const float b2k = b2[lane];
    const float b3v = b3[0];
    // exp2-folded variants for tanh_fast
    const float cW_s  = cW  * C_2L2E;
    const float cT_s  = cT  * C_2L2E;
    const float cYw_s = cYw * C_2L2E;
    const float b1_s  = b1k * C_2L2E;
    const float b2_s  = b2k * C_2L2E;
    // packed-f16 jet constants (-2 folded into the ddp products)
    const h2 cWh  = pk2(cW, cW);
    const h2 cYwh = pk2(cYw, cYw);
    const h2 cW2m = pk2(-2.0f*cW*cW,  -2.0f*cW*cW);
    const h2 cWYm = pk2(-2.0f*cW*cYw, -2.0f*cW*cYw);
    const h2 hone = {(_Float16)1.0f,  (_Float16)1.0f};
    const h2 m2h  = {(_Float16)-2.0f, (_Float16)-2.0f};

    // MFMA B fragments (f16): B[k][n], n=mrow+t*16, k=q*32+quad*8+j
    half8 B00, B01, B02, B03, B10, B11, B12, B13, W30, W31;
    {
        half8 h;
        #define LOADB(dst, q, t) \
            { for (int j = 0; j < 8; ++j) \
                h[j] = (_Float16)w2[((q)*32 + quad*8 + j)*HID + (t)*16 + mrow]; \
              dst = h; }
        LOADB(B00, 0, 0) LOADB(B01, 0, 1) LOADB(B02, 0, 2) LOADB(B03, 0, 3)
        LOADB(B10, 1, 0) LOADB(B11, 1, 1) LOADB(B12, 1, 2) LOADB(B13, 1, 3)
        #undef LOADB
        for (int j = 0; j < 8; ++j) h[j] = (_Float16)w3[0*32 + quad*8 + j];
        W30 = h;
        for (int j = 0; j < 8; ++j) h[j] = (_Float16)w3[1*32 + quad*8 + j];
        W31 = h;
    }

    // zero A-buffer once (rows 5-7, 13-15 must stay zero)
    for (int off = lane*4; off < 16*A_ROW; off += 256)
        *(float*)(wb + off) = 0.0f;

    // LDS addresses
    _Float16* swp = (_Float16*)(wb + lane*2);   // + row*72 elements
    char* arp0 = wb + mrow*A_ROW + quad*16;     // A-frag k-iter 0 (+64 B for iter 1)

    // per-lane noise pointers (half-wave uniform)
    const float* zp1 = noise + (size_t)(simb*2 + 0) * MSTEPS * BTOT + pg;
    const float* zp2 = noise + (size_t)(simb*2 + 1) * MSTEPS * BTOT + pg;

    // ---- precomputed dynamics coefficients (fold anti & constants)
    const float anti = simb ? -1.0f : 1.0f;
    const float ksa  = C_SIGMA * C_ALPHA;
    const float ks2  = C_SIGMA * C_SIGMA;
    const float ksn  = anti * C_SIGMA * C_SQDT;
    const float kFy  = ksa * C_DT;
    const float ksd  = ks2 * C_DT;
    const float kv   = 0.5f * ks2 * C_DT;
    const float kRdt = C_R * C_DT;
    const float ky1  = anti * C_SIGY * C_SQDT * C_RHO;
    const float ky2  = anti * C_SIGY * C_SQDT * C_SQ1MR2;
    const float cYfac = 1.0f - C_KAPPA * C_DT;

    // per-lane path state + jets of L = logW
    const float W0 = Wp[i];
    float L   = __logf(fmaxf(W0, C_LBW));
    float W   = __expf(L);
    float Yv  = Yp[i];
    float tmt = 1.5f;
    float gW  = 1.0f / W0;
    float hWW = -gW * gW;
    float gY  = 0.0f, hWY = 0.0f;
    float cYt = 1.0f;

    // software-pipelined noise (issue next step's loads a full body ahead)
    float z1c = zp1[0];
    float z2c = zp2[0];

    #pragma unroll 1
    for (int m = 0; m < MSTEPS; ++m) {
        asm volatile("" : "+v"(B00), "+v"(B01), "+v"(B02), "+v"(B03),
                          "+v"(B10), "+v"(B11), "+v"(B12), "+v"(B13),
                          "+v"(W30), "+v"(W31));

        const float z1 = z1c, z2 = z2c;
        const int mn = (m + 1 < MSTEPS) ? m + 1 : m;
        z1c = zp1[(size_t)mn * BTOT];
        z2c = zp2[(size_t)mn * BTOT];

        // broadcast both paths' (W,Y): path0 state in lane 0, path1 in lane 32
        const float Wb0 = rlanef(W, 0),  Wb1 = rlanef(W, 32);
        const float Yb0 = rlanef(Yv, 0), Yb1 = rlanef(Yv, 32);

        // ---- layer 1 + tanh, both paths packed f16; marshal A rows 8p..8p+4
        const float base1s = fmaf(tmt, cT_s, b1_s);
        {
            const float t10 = tanh_fast(fmaf(Wb0, cW_s, fmaf(Yb0, cYw_s, base1s)));
            const float t11 = tanh_fast(fmaf(Wb1, cW_s, fmaf(Yb1, cYw_s, base1s)));
            const h2 tp  = pk2(t10, t11);
            const h2 dpp = hone - tp * tp;      // v_pk_fma
            const h2 ddq = tp * dpp;            // (-2) folded into cW2m/cWYm
            const h2 r1 = dpp * cWh;
            const h2 r2 = dpp * cYwh;
            const h2 r3 = ddq * cW2m;
            const h2 r4 = ddq * cWYm;
            swp[0*72] = tp.x;  swp[8*72]  = tp.y;   // hi halves -> ds_write_b16_d16_hi
            swp[1*72] = r1.x;  swp[9*72]  = r1.y;
            swp[2*72] = r2.x;  swp[10*72] = r2.y;
            swp[3*72] = r3.x;  swp[11*72] = r3.y;
            swp[4*72] = r4.x;  swp[12*72] = r4.y;
        }

        half8 af0 = __builtin_bit_cast(half8, *(const f32x4*)arp0);
        half8 af1 = __builtin_bit_cast(half8, *(const f32x4*)(arp0 + 64));

        // ---- layer 2 GEMM: 4 N-tiles x 2 K-iters
        f32x4 acc[4];
        const f32x4 zz = {0.f, 0.f, 0.f, 0.f};
        acc[0] = MFMA(af1, B10, MFMA(af0, B00, zz));
        acc[1] = MFMA(af1, B11, MFMA(af0, B01, zz));
        acc[2] = MFMA(af1, B12, MFMA(af0, B02, zz));
        acc[3] = MFMA(af1, B13, MFMA(af0, B03, zz));

        // ---- D transpose via LDS in raw f32 (no pack/perm VALU on this path)
        {
            const int p = quad >> 1;
            if (!(quad & 1)) {
                #pragma unroll
                for (int t = 0; t < 4; ++t)
                    *(f32x4*)(wb + OFF_DV + ((t*16 + mrow) << 5) + (p << 4)) = acc[t];
            } else {
                #pragma unroll
                for (int t = 0; t < 4; ++t)
                    *(float*)(wb + OFF_DA + ((t*16 + mrow) << 3) + (p << 2)) =
                        acc[t].x;
            }
        }

        // ---- per-lane (unit k): read both paths' activations in f32,
        // pack once, compute layer-2 jets packed f16, marshal rows 0-4/8-12
        const f32x4 v0 = *(const f32x4*)(wb + OFF_DV + (lane << 5));
        const f32x4 v1 = *(const f32x4*)(wb + OFF_DV + (lane << 5) + 16);
        const float2 aw = *(const float2*)(wb + OFF_DA + (lane << 3));
        {
            const h2 aWp  = pk2(v0.y, v1.y);
            const h2 aYp  = pk2(v0.z, v1.z);
            const h2 aWWp = pk2(v0.w, v1.w);
            const h2 awyp = pk2(aw.x, aw.y);
            const float t20 = tanh_fast(fmaf(v0.x, C_2L2E, b2_s));
            const float t21 = tanh_fast(fmaf(v1.x, C_2L2E, b2_s));
            const h2 t2p = pk2(t20, t21);
            const h2 d2p = hone - t2p * t2p;
            const h2 qp  = (m2h * (t2p * d2p)) * aWp;   // dd2 * aW
            const h2 s1 = d2p * aWp;
            const h2 s2 = d2p * aYp;
            const h2 s3 = qp * aWp + d2p * aWWp;
            const h2 s4 = qp * aYp + d2p * awyp;
            swp[0*72] = t2p.x; swp[8*72]  = t2p.y;
            swp[1*72] = s1.x;  swp[9*72]  = s1.y;
            swp[2*72] = s2.x;  swp[10*72] = s2.y;
            swp[3*72] = s3.x;  swp[11*72] = s3.y;
            swp[4*72] = s4.x;  swp[12*72] = s4.y;
        }

        // ---- layer 3 via MFMA (w3 broadcast over n -> all cols equal)
        half8 bf0 = __builtin_bit_cast(half8, *(const f32x4*)arp0);
        half8 bf1 = __builtin_bit_cast(half8, *(const f32x4*)(arp0 + 64));
        f32x4 acc4 = MFMA(bf1, W31, MFMA(bf0, W30, zz));

        // ---- policy-jet broadcast via ds_swizzle (static crossbar, 32-lane
        // groups — no LDS memory round trip, no bank conflicts):
        // rows 8p..8p+3 live in lane 32p regs x..w -> offset 0x0000 (group lane 0)
        // row 8p+4 lives in lane 32p+16 reg x      -> offset 0x0200 (group lane 16)
        const float pi  = swz<0x0000>(acc4.x) + b3v;
        const float pW  = swz<0x0000>(acc4.y);
        const float pY  = swz<0x0000>(acc4.z);
        const float pWW = swz<0x0000>(acc4.w);
        const float pWY = swz<0x0200>(acc4.x);

        // ---- dynamics + jet update (refactored: shared GdtSn factor)
        const float Sn    = ksn * z1;
        const float say   = ksa * Yv;
        const float G     = fmaf(-ks2, pi, say);
        const float GdtSn = fmaf(G, C_DT, Sn);

        const float w2v  = W * W;
        const float piL  = pW * W;
        const float piLL = fmaf(pWW, w2v, piL);
        const float piY  = pY;
        const float piLY = pWY * W;

        const float pi2  = pi * pi;
        const float Lnew = fmaf(pi, fmaf(say, C_DT, Sn),
                                fmaf(-kv, pi2, L + kRdt));

        const float F_L  = fmaf(piL, GdtSn, 1.0f);
        const float F_Y  = fmaf(piY, GdtSn, kFy * pi);
        const float piL2 = piL * piL;
        const float F_LL = fmaf(piLL, GdtSn, -(ksd * piL2));
        const float F_LY = fmaf(piLY, GdtSn, piL * fmaf(-ksd, piY, kFy));

        const float gW2  = gW * gW;
        const float hWWn = fmaf(F_LL, gW2, F_L * hWW);
        const float hWYn = fmaf(F_LL, gW * gY,
                                fmaf(F_LY, gW * cYt, F_L * hWY));
        const float gWn  = F_L * gW;
        const float gYn  = fmaf(F_Y, cYt, F_L * gY);

        Yv  = fmaf(ky2, z2, fmaf(ky1, z1, cYfac * Yv));
        cYt *= cYfac;

        const float We   = __expf(Lnew);
        const bool  clip = (We < C_LBW);
        L   = clip ? C_LOGLBW : Lnew;
        W   = clip ? C_LBW    : We;
        gW  = clip ? 0.0f : gWn;
        gY  = clip ? 0.0f : gYn;
        hWW = clip ? 0.0f : hWWn;
        hWY = clip ? 0.0f : hWYn;
        tmt -= C_DT;
    }

    // terminal utility U = -0.25*exp(-4L); direct per-branch store (no atomics)
    const float E   = __expf(-4.0f * L);
    const float d1  = E * gW;
    const float d2v = fmaf(-4.0f * E, gW * gW, E * hWW);
    const float d3v = fmaf(-4.0f * E, gW * gY, E * hWY);

    if ((lane & 31) == 0) {   // lane 0 = path 2w', lane 32 = path 2w'+1
        const int branch = simb * BTOT + pg;      // 0..8191, branch&31 == i
        sd[         branch] = 0.5f * d1;
        sd[  NSIM + branch] = 0.5f * d2v;
        sd[2*NSIM + branch] = 0.5f * d3v;
    }

    // ---- fused projection: last block to finish does the reduction.
    // Ticket counter is monotonically increasing; (old & 1023)==1023 selects
    // exactly one block per 1024 arrivals regardless of initial value, so the
    // workspace never needs zeroing (graph-replay safe). Device-scope fences
    // handle cross-XCD L2 visibility (G16).
    __threadfence();                  // release: push sd stores device-visible
    __syncthreads();
    if (threadIdx.x == 0) {
        const unsigned old = atomicAdd(cnt, 1u);   // device-scope by default
        lastf = ((old & (NBLK - 1u)) == (NBLK - 1u)) ? 1 : 0;
    }
    __syncthreads();
    if (lastf) {
        __threadfence();              // acquire: invalidate stale L2 lines
        float* red = (float*)smem;    // reuse block LDS (>= 3 KiB needed)
        const int tid = threadIdx.x;
        const int ii  = tid & 31;     // eval point
        const int c   = tid >> 5;     // chunk 0..7
        float lam = 0.f, dWs = 0.f, dYs = 0.f;
        #pragma unroll 4
        for (int jj = 0; jj < 32; ++jj) {           // 256 entries per point
            const int idx = ii + ((jj*8 + c) << 5); // coalesced
            lam += sd[idx];
            dWs += sd[NSIM + idx];
            dYs += sd[2*NSIM + idx];
        }
        red[tid] = lam; red[256 + tid] = dWs; red[512 + tid] = dYs;
        __syncthreads();
        if (tid < NPTS) {
            float l = 0.f, wv = 0.f, y = 0.f;
            #pragma unroll
            for (int c2 = 0; c2 < 8; ++c2) {
                l  += red[c2*32 + ii];
                wv += red[256 + c2*32 + ii];
                y  += red[512 + c2*32 + ii];
            }
            l  *= (1.0f / 2097152.0f);     // /128^3
            wv *= (1.0f / 268435456.0f);   // /128^4
            y  *= (1.0f / 268435456.0f);
            const float Wv = Wp[ii], Yvv = Yp[ii];
            const float mmr   = C_SIGMA * (C_ALPHA * Yvv);
            const float sig2  = C_SIGMA * C_SIGMA;
            const float coeff = -1.0f / (Wv * wv + 1e-8f);
            const float myo   = coeff * (l * (mmr / sig2));
            const float hedge = coeff * (C_SIGMA * C_RHO * C_SIGY * y / sig2);
            float v = myo + hedge;
            v = fminf(fmaxf(v, -2.0f), 2.0f);
            out[ii] = v;
        }
    }
}

extern "C" void kernel_launch(void* const* d_in, const int* in_sizes, int n_in,
                              void* d_out, int out_size, void* d_ws, size_t ws_size,
                              hipStream_t stream) {
    const float* Wp    = (const float*)d_in[0];
    // d_in[1] = TmT (unused: reference simulates from T_H constant)
    const float* Yp    = (const float*)d_in[2];
    const float* noise = (const float*)d_in[3];
    const float* w1    = (const float*)d_in[4];
    const float* b1    = (const float*)d_in[5];
    const float* w2    = (const float*)d_in[6];
    const float* b2    = (const float*)d_in[7];
    const float* w3    = (const float*)d_in[8];
    const float* b3    = (const float*)d_in[9];
    float* out = (float*)d_out;
    float* sd  = (float*)d_ws;                                // 3*8192 floats
    unsigned int* cnt = (unsigned int*)((char*)d_ws + 3*NSIM*sizeof(float));

    hipLaunchKernelGGL(sim_kernel, dim3(NBLK), dim3(256), 0, stream,
                       noise, w1, b1, w2, b2, w3, b3, Wp, Yp, sd, cnt, out);
}

// Round 4
// 171.797 us; speedup vs baseline: 1.3156x; 1.3156x over previous
//
#include <hip/hip_runtime.h>
#include <math.h>

#define HID    64
#define MSTEPS 60
#define NPTS   32
#define RPTSC  128
#define BTOT   (RPTSC*NPTS)    // 4096 paths
#define NSIM   (2*BTOT)        // 8192 path-branches
#define NWAVE  2048            // waves: 2 path-pairs (4 branches) per wave
#define NBLK   (NWAVE/4)       // 512 blocks

// hard-coded model constants (match reference, fp32 semantics)
#define C_DT     0.025f
#define C_SQDT   0.15811388300841897f   // sqrt(0.025)
#define C_ALPHA  0.8f
#define C_RHO    0.3f
#define C_SQ1MR2 0.9539392014169456f    // sqrt(1-0.09)
#define C_KAPPA  1.2f
#define C_R      0.02f
#define C_SIGMA  0.2f
#define C_SIGY   0.3f
#define C_LBW    1e-3f
#define C_LOGLBW -6.907755279f          // log(1e-3)
#define C_2L2E   2.8853900817779268f    // 2*log2(e): tanh(x)=1-2/(2^(x*2L2E)+1)

// per-PAIR LDS layout (two per wave):
//   [0,2304)      A-buffer: 16 rows x 144 B (64 f16 + 16 B pad)
//   [2304,3328)   DV: per unit u: [u*16 + p*8] int2 of f16 (a0,aW | aY,aWW)
//   [3328,3584)   DA: per unit u: [u*4 + p*2] f16 aWY  (path-interleaved)
#define PAIR_LDS 3584
#define A_ROW    144
#define OFF_DV   2304
#define OFF_DA   3328

typedef _Float16 half8 __attribute__((ext_vector_type(8)));
typedef float    f32x4 __attribute__((ext_vector_type(4)));
typedef _Float16 h2    __attribute__((ext_vector_type(2)));

__device__ __forceinline__ float rlanef(float v, int l) {
    return __int_as_float(__builtin_amdgcn_readlane(__float_as_int(v), l));
}
// static-pattern lane crossbar within 32-lane groups (BitMode):
// src_lane = ((lane & and) | or) ^ xor ; offset = (xor<<10)|(or<<5)|and
template <int OFF>
__device__ __forceinline__ float swz(float v) {
    return __int_as_float(__builtin_amdgcn_ds_swizzle(__float_as_int(v), OFF));
}
__device__ __forceinline__ f32x4 MFMA(half8 a, half8 b, f32x4 c) {
    return __builtin_amdgcn_mfma_f32_16x16x32_f16(a, b, c, 0, 0, 0);
}
// pack two f32 -> f16x2 (RTZ) as int
__device__ __forceinline__ int pk16(float a, float b) {
    return __builtin_bit_cast(int, __builtin_amdgcn_cvt_pkrtz(a, b));
}
__device__ __forceinline__ h2 pk2(float a, float b) {
    return __builtin_bit_cast(h2, __builtin_amdgcn_cvt_pkrtz(a, b));
}
// v_perm_b32 byte gather: sel byte<4 picks from s1, >=4 picks from s0
__device__ __forceinline__ h2 permh(unsigned s0, unsigned s1, unsigned sel) {
    return __builtin_bit_cast(h2, __builtin_amdgcn_perm(s0, s1, sel));
}
// tanh with argument pre-scaled by 2*log2(e): tanh = 1 - 2/(2^xs + 1)
__device__ __forceinline__ float tanh_fast(float xs) {
    return 1.0f - 2.0f * __builtin_amdgcn_rcpf(__builtin_amdgcn_exp2f(xs) + 1.0f);
}

// layer-1 jets for one pair, marshal A rows 0-4 (par0) / 8-12 (par1)
__device__ __forceinline__ void l1_jets(
    _Float16* swp, float bW0, float bW1, float bY0, float bY1,
    float base1s, float cW_s, float cYw_s,
    h2 cWh, h2 cYwh, h2 cW2m, h2 cWYm)
{
    const h2 hone = {(_Float16)1.0f, (_Float16)1.0f};
    const float t10 = tanh_fast(fmaf(bW0, cW_s, fmaf(bY0, cYw_s, base1s)));
    const float t11 = tanh_fast(fmaf(bW1, cW_s, fmaf(bY1, cYw_s, base1s)));
    const h2 tp  = pk2(t10, t11);
    const h2 dpp = hone - tp * tp;      // v_pk_fma
    const h2 ddq = tp * dpp;            // (-2) folded into cW2m/cWYm
    const h2 r1 = dpp * cWh;
    const h2 r2 = dpp * cYwh;
    const h2 r3 = ddq * cW2m;
    const h2 r4 = ddq * cWYm;
    swp[0*72] = tp.x;  swp[8*72]  = tp.y;   // hi halves -> ds_write_b16_d16_hi
    swp[1*72] = r1.x;  swp[9*72]  = r1.y;
    swp[2*72] = r2.x;  swp[10*72] = r2.y;
    swp[3*72] = r3.x;  swp[11*72] = r3.y;
    swp[4*72] = r4.x;  swp[12*72] = r4.y;
}

// D transpose via LDS, packed f16, path-interleaved per unit
__device__ __forceinline__ void dxpose(char* wb, const f32x4* acc, int quad, int mrow)
{
    const int p = quad >> 1;
    if (!(quad & 1)) {
        #pragma unroll
        for (int t = 0; t < 4; ++t) {
            int2 v;
            v.x = pk16(acc[t].x, acc[t].y);
            v.y = pk16(acc[t].z, acc[t].w);
            *(int2*)(wb + OFF_DV + ((t*16 + mrow) << 4) + (p << 3)) = v;
        }
    } else {
        #pragma unroll
        for (int t = 0; t < 4; ++t)
            *(_Float16*)(wb + OFF_DA + ((t*16 + mrow) << 2) + (p << 1)) =
                (_Float16)acc[t].x;
    }
}

// layer-2 jets (per-lane unit k, both paths packed), marshal rows 0-4/8-12
__device__ __forceinline__ void l2_jets(_Float16* swp, f32x4 dvv, h2 awyp, float b2_s)
{
    const h2 hone = {(_Float16)1.0f,  (_Float16)1.0f};
    const h2 m2h  = {(_Float16)-2.0f, (_Float16)-2.0f};
    const unsigned q0 = __builtin_bit_cast(unsigned, dvv.x); // p0 (a0,aW)
    const unsigned q1 = __builtin_bit_cast(unsigned, dvv.y); // p0 (aY,aWW)
    const unsigned q2 = __builtin_bit_cast(unsigned, dvv.z); // p1 (a0,aW)
    const unsigned q3 = __builtin_bit_cast(unsigned, dvv.w); // p1 (aY,aWW)
    const h2 a0p  = permh(q2, q0, 0x05040100);
    const h2 aWp  = permh(q2, q0, 0x07060302);
    const h2 aYp  = permh(q3, q1, 0x05040100);
    const h2 aWWp = permh(q3, q1, 0x07060302);

    const float t20 = tanh_fast(fmaf((float)a0p.x, C_2L2E, b2_s));
    const float t21 = tanh_fast(fmaf((float)a0p.y, C_2L2E, b2_s));
    const h2 t2p = pk2(t20, t21);
    const h2 d2p = hone - t2p * t2p;
    const h2 qp  = (m2h * (t2p * d2p)) * aWp;   // dd2 * aW
    const h2 s1 = d2p * aWp;
    const h2 s2 = d2p * aYp;
    const h2 s3 = qp * aWp + d2p * aWWp;
    const h2 s4 = qp * aYp + d2p * awyp;
    swp[0*72] = t2p.x; swp[8*72]  = t2p.y;
    swp[1*72] = s1.x;  swp[9*72]  = s1.y;
    swp[2*72] = s2.x;  swp[10*72] = s2.y;
    swp[3*72] = s3.x;  swp[11*72] = s3.y;
    swp[4*72] = s4.x;  swp[12*72] = s4.y;
}

// sim: 2 independent path-pairs per wave (in-wave ILP to fill the lockstep
// LDS-turnaround stall windows seen at 1 pair/wave). Per-branch derivative
// stores, no atomics. sd[c*NSIM + branch], branch & 31 == eval point.
__global__ __launch_bounds__(256, 2) void sim_kernel(
    const float* __restrict__ noise,
    const float* __restrict__ w1, const float* __restrict__ b1,
    const float* __restrict__ w2, const float* __restrict__ b2,
    const float* __restrict__ w3, const float* __restrict__ b3,
    const float* __restrict__ Wp, const float* __restrict__ Yp,
    float* __restrict__ sd)
{
    __shared__ __align__(16) char smem[4 * 2 * PAIR_LDS];
    const int lane = threadIdx.x & 63;
    const int quad = lane >> 4;      // 0..3
    const int mrow = lane & 15;      // 0..15
    const int par  = lane >> 5;      // path half within a pair
    char* wbA = smem + (threadIdx.x >> 6) * (2 * PAIR_LDS);
    char* wbB = wbA + PAIR_LDS;

    const int w = __builtin_amdgcn_readfirstlane(
        (int)((blockIdx.x * blockDim.x + threadIdx.x) >> 6));   // 0..2047
    const int simb = w >> 10;                 // antithetic branch (wave-uniform)
    const int pga  = 4*(w & 1023) + par;      // pair A per-lane path
    const int pgb  = pga + 2;                 // pair B per-lane path
    const int ia   = pga & (NPTS - 1);
    const int ib   = pgb & (NPTS - 1);

    // per-lane layer-1 weights (lane = hidden unit)
    const float cW  = w1[lane];
    const float cT  = w1[HID + lane];
    const float cYw = w1[2*HID + lane];
    const float b1k = b1[lane];
    const float b2k = b2[lane];
    const float b3v = b3[0];
    // exp2-folded variants for tanh_fast
    const float cW_s  = cW  * C_2L2E;
    const float cT_s  = cT  * C_2L2E;
    const float cYw_s = cYw * C_2L2E;
    const float b1_s  = b1k * C_2L2E;
    const float b2_s  = b2k * C_2L2E;
    // packed-f16 jet constants (-2 folded into the ddp products)
    const h2 cWh  = pk2(cW, cW);
    const h2 cYwh = pk2(cYw, cYw);
    const h2 cW2m = pk2(-2.0f*cW*cW,  -2.0f*cW*cW);
    const h2 cWYm = pk2(-2.0f*cW*cYw, -2.0f*cW*cYw);

    // MFMA B fragments (f16): B[k][n], n=mrow+t*16, k=q*32+quad*8+j
    half8 B00, B01, B02, B03, B10, B11, B12, B13, W30, W31;
    {
        half8 h;
        #define LOADB(dst, q, t) \
            { for (int j = 0; j < 8; ++j) \
                h[j] = (_Float16)w2[((q)*32 + quad*8 + j)*HID + (t)*16 + mrow]; \
              dst = h; }
        LOADB(B00, 0, 0) LOADB(B01, 0, 1) LOADB(B02, 0, 2) LOADB(B03, 0, 3)
        LOADB(B10, 1, 0) LOADB(B11, 1, 1) LOADB(B12, 1, 2) LOADB(B13, 1, 3)
        #undef LOADB
        for (int j = 0; j < 8; ++j) h[j] = (_Float16)w3[0*32 + quad*8 + j];
        W30 = h;
        for (int j = 0; j < 8; ++j) h[j] = (_Float16)w3[1*32 + quad*8 + j];
        W31 = h;
    }

    // zero both A-buffers once (rows 5-7, 13-15 must stay zero)
    for (int off = lane*4; off < 16*A_ROW; off += 256) {
        *(float*)(wbA + off) = 0.0f;
        *(float*)(wbB + off) = 0.0f;
    }

    // LDS addresses
    _Float16* swpA = (_Float16*)(wbA + lane*2);   // + row*72 elements
    _Float16* swpB = (_Float16*)(wbB + lane*2);
    char* arpA = wbA + mrow*A_ROW + quad*16;      // A-frag k-iter 0 (+64 B iter 1)
    char* arpB = wbB + mrow*A_ROW + quad*16;

    // per-lane noise pointers (half-wave uniform); pair B = +2 elements
    const float* zp1 = noise + (size_t)(simb*2 + 0) * MSTEPS * BTOT + pga;
    const float* zp2 = noise + (size_t)(simb*2 + 1) * MSTEPS * BTOT + pga;

    // ---- precomputed dynamics coefficients (fold anti & constants)
    const float anti = simb ? -1.0f : 1.0f;
    const float ksa  = C_SIGMA * C_ALPHA;
    const float ks2  = C_SIGMA * C_SIGMA;
    const float ksn  = anti * C_SIGMA * C_SQDT;
    const float kFy  = ksa * C_DT;
    const float ksd  = ks2 * C_DT;
    const float kv   = 0.5f * ks2 * C_DT;
    const float kRdt = C_R * C_DT;
    const float ky1  = anti * C_SIGY * C_SQDT * C_RHO;
    const float ky2  = anti * C_SIGY * C_SQDT * C_SQ1MR2;
    const float cYfac = 1.0f - C_KAPPA * C_DT;

    // per-pair path state + jets of L = logW (cYt, tmt deterministic: shared)
    const float W0a = Wp[ia], W0b = Wp[ib];
    float La = __logf(fmaxf(W0a, C_LBW)), Lb = __logf(fmaxf(W0b, C_LBW));
    float Wa = __expf(La),                Wb = __expf(Lb);
    float Ya = Yp[ia],                    Yb = Yp[ib];
    float gWa = 1.0f / W0a,               gWb = 1.0f / W0b;
    float hWWa = -gWa * gWa,              hWWb = -gWb * gWb;
    float gYa = 0.0f, hWYa = 0.0f,        gYb = 0.0f, hWYb = 0.0f;
    float tmt = 1.5f;
    float cYt = 1.0f;

    // software-pipelined noise (issue next step's loads a full body ahead)
    float z1ca = zp1[0], z2ca = zp2[0];
    float z1cb = zp1[2], z2cb = zp2[2];

    // dynamics + jet update for one pair (captures coefficients + cYt)
    auto dyn = [&](float& L, float& W, float& Yv, float& gW, float& gY,
                   float& hWW, float& hWY, float z1, float z2,
                   float pi, float pW, float pY, float pWW, float pWY) {
        const float Sn    = ksn * z1;
        const float say   = ksa * Yv;
        const float G     = fmaf(-ks2, pi, say);
        const float GdtSn = fmaf(G, C_DT, Sn);

        const float w2v  = W * W;
        const float piL  = pW * W;
        const float piLL = fmaf(pWW, w2v, piL);
        const float piY  = pY;
        const float piLY = pWY * W;

        const float pi2  = pi * pi;
        const float Lnew = fmaf(pi, fmaf(say, C_DT, Sn),
                                fmaf(-kv, pi2, L + kRdt));

        const float F_L  = fmaf(piL, GdtSn, 1.0f);
        const float F_Y  = fmaf(piY, GdtSn, kFy * pi);
        const float piL2 = piL * piL;
        const float F_LL = fmaf(piLL, GdtSn, -(ksd * piL2));
        const float F_LY = fmaf(piLY, GdtSn, piL * fmaf(-ksd, piY, kFy));

        const float gW2  = gW * gW;
        const float hWWn = fmaf(F_LL, gW2, F_L * hWW);
        const float hWYn = fmaf(F_LL, gW * gY,
                                fmaf(F_LY, gW * cYt, F_L * hWY));
        const float gWn  = F_L * gW;
        const float gYn  = fmaf(F_Y, cYt, F_L * gY);

        Yv = fmaf(ky2, z2, fmaf(ky1, z1, cYfac * Yv));

        const float We   = __expf(Lnew);
        const bool  clip = (We < C_LBW);
        L   = clip ? C_LOGLBW : Lnew;
        W   = clip ? C_LBW    : We;
        gW  = clip ? 0.0f : gWn;
        gY  = clip ? 0.0f : gYn;
        hWW = clip ? 0.0f : hWWn;
        hWY = clip ? 0.0f : hWYn;
    };

    #pragma unroll 1
    for (int m = 0; m < MSTEPS; ++m) {
        asm volatile("" : "+v"(B00), "+v"(B01), "+v"(B02), "+v"(B03),
                          "+v"(B10), "+v"(B11), "+v"(B12), "+v"(B13),
                          "+v"(W30), "+v"(W31));

        const float z1a = z1ca, z2a = z2ca, z1b = z1cb, z2b = z2cb;
        const int mn = (m + 1 < MSTEPS) ? m + 1 : m;
        z1ca = zp1[(size_t)mn * BTOT];     z2ca = zp2[(size_t)mn * BTOT];
        z1cb = zp1[(size_t)mn * BTOT + 2]; z2cb = zp2[(size_t)mn * BTOT + 2];

        // broadcast both pairs' (W,Y): par0 state in lane 0, par1 in lane 32
        const float bWa0 = rlanef(Wa, 0), bWa1 = rlanef(Wa, 32);
        const float bYa0 = rlanef(Ya, 0), bYa1 = rlanef(Ya, 32);
        const float bWb0 = rlanef(Wb, 0), bWb1 = rlanef(Wb, 32);
        const float bYb0 = rlanef(Yb, 0), bYb1 = rlanef(Yb, 32);

        // ---- layer 1 + tanh + A marshal, both pairs (independent chains)
        const float base1s = fmaf(tmt, cT_s, b1_s);
        l1_jets(swpA, bWa0, bWa1, bYa0, bYa1, base1s, cW_s, cYw_s,
                cWh, cYwh, cW2m, cWYm);
        l1_jets(swpB, bWb0, bWb1, bYb0, bYb1, base1s, cW_s, cYw_s,
                cWh, cYwh, cW2m, cWYm);

        half8 afA0 = __builtin_bit_cast(half8, *(const f32x4*)arpA);
        half8 afA1 = __builtin_bit_cast(half8, *(const f32x4*)(arpA + 64));
        half8 afB0 = __builtin_bit_cast(half8, *(const f32x4*)arpB);
        half8 afB1 = __builtin_bit_cast(half8, *(const f32x4*)(arpB + 64));

        // ---- layer 2 GEMM: 4 N-tiles x 2 K-iters, both pairs
        f32x4 accA[4], accB[4];
        const f32x4 zz = {0.f, 0.f, 0.f, 0.f};
        accA[0] = MFMA(afA1, B10, MFMA(afA0, B00, zz));
        accB[0] = MFMA(afB1, B10, MFMA(afB0, B00, zz));
        accA[1] = MFMA(afA1, B11, MFMA(afA0, B01, zz));
        accB[1] = MFMA(afB1, B11, MFMA(afB0, B01, zz));
        accA[2] = MFMA(afA1, B12, MFMA(afA0, B02, zz));
        accB[2] = MFMA(afB1, B12, MFMA(afB0, B02, zz));
        accA[3] = MFMA(afA1, B13, MFMA(afA0, B03, zz));
        accB[3] = MFMA(afB1, B13, MFMA(afB0, B03, zz));

        // ---- D transpose via LDS, packed f16
        dxpose(wbA, accA, quad, mrow);
        dxpose(wbB, accB, quad, mrow);

        // ---- per-lane (unit k) readback + layer-2 jets + A marshal
        const f32x4 dvA = *(const f32x4*)(wbA + OFF_DV + (lane << 4));
        const h2   awA  = *(const h2*)  (wbA + OFF_DA + (lane << 2));
        const f32x4 dvB = *(const f32x4*)(wbB + OFF_DV + (lane << 4));
        const h2   awB  = *(const h2*)  (wbB + OFF_DA + (lane << 2));
        l2_jets(swpA, dvA, awA, b2_s);
        l2_jets(swpB, dvB, awB, b2_s);

        // ---- layer 3 via MFMA (w3 broadcast over n -> all cols equal)
        half8 bfA0 = __builtin_bit_cast(half8, *(const f32x4*)arpA);
        half8 bfA1 = __builtin_bit_cast(half8, *(const f32x4*)(arpA + 64));
        half8 bfB0 = __builtin_bit_cast(half8, *(const f32x4*)arpB);
        half8 bfB1 = __builtin_bit_cast(half8, *(const f32x4*)(arpB + 64));
        f32x4 acc4A = MFMA(bfA1, W31, MFMA(bfA0, W30, zz));
        f32x4 acc4B = MFMA(bfB1, W31, MFMA(bfB0, W30, zz));

        // ---- policy-jet broadcast via ds_swizzle (static crossbar, 32-lane
        // groups): rows 8p..8p+3 live in group lane 0 regs x..w -> 0x0000;
        // row 8p+4 lives in group lane 16 reg x -> 0x0200.
        const float piA  = swz<0x0000>(acc4A.x) + b3v;
        const float pWA  = swz<0x0000>(acc4A.y);
        const float pYA  = swz<0x0000>(acc4A.z);
        const float pWWA = swz<0x0000>(acc4A.w);
        const float pWYA = swz<0x0200>(acc4A.x);
        const float piB  = swz<0x0000>(acc4B.x) + b3v;
        const float pWB  = swz<0x0000>(acc4B.y);
        const float pYB  = swz<0x0000>(acc4B.z);
        const float pWWB = swz<0x0000>(acc4B.w);
        const float pWYB = swz<0x0200>(acc4B.x);

        // ---- dynamics + jet update, both pairs
        dyn(La, Wa, Ya, gWa, gYa, hWWa, hWYa, z1a, z2a,
            piA, pWA, pYA, pWWA, pWYA);
        dyn(Lb, Wb, Yb, gWb, gYb, hWWb, hWYb, z1b, z2b,
            piB, pWB, pYB, pWWB, pWYB);

        cYt *= cYfac;
        tmt -= C_DT;
    }

    // terminal utility U = -0.25*exp(-4L); direct per-branch store (no atomics)
    if ((lane & 31) == 0) {   // lane 0 = par0 path, lane 32 = par1 path
        const int brA = simb * BTOT + pga;    // branch & 31 == eval point
        const int brB = brA + 2;
        {
            const float E = __expf(-4.0f * La);
            sd[         brA] = 0.5f * (E * gWa);
            sd[  NSIM + brA] = 0.5f * fmaf(-4.0f * E, gWa * gWa, E * hWWa);
            sd[2*NSIM + brA] = 0.5f * fmaf(-4.0f * E, gWa * gYa, E * hWYa);
        }
        {
            const float E = __expf(-4.0f * Lb);
            sd[         brB] = 0.5f * (E * gWb);
            sd[  NSIM + brB] = 0.5f * fmaf(-4.0f * E, gWb * gWb, E * hWWb);
            sd[2*NSIM + brB] = 0.5f * fmaf(-4.0f * E, gWb * gYb, E * hWYb);
        }
    }
}

// 512 threads: 16 chunk-accumulators per eval point, LDS tree reduce.
__global__ __launch_bounds__(512) void proj_kernel(
    const float* __restrict__ sd,
    const float* __restrict__ Wp,
    const float* __restrict__ Yp,
    float* __restrict__ out)
{
    __shared__ float red[3 * 512];
    const int tid = threadIdx.x;
    const int i = tid & 31;
    const int c = tid >> 5;           // 0..15
    float lam = 0.f, dW = 0.f, dY = 0.f;
    #pragma unroll 4
    for (int jj = 0; jj < 16; ++jj) {            // 256 chunks of 32 floats total
        const int idx = i + ((jj*16 + c) << 5);  // coalesced 128B per 32 lanes
        lam += sd[idx];
        dW  += sd[NSIM + idx];
        dY  += sd[2*NSIM + idx];
    }
    red[tid] = lam; red[512 + tid] = dW; red[1024 + tid] = dY;
    __syncthreads();
    if (tid < NPTS) {
        float l = 0.f, w = 0.f, y = 0.f;
        #pragma unroll
        for (int c2 = 0; c2 < 16; ++c2) {
            l += red[c2*32 + i];
            w += red[512 + c2*32 + i];
            y += red[1024 + c2*32 + i];
        }
        l *= (1.0f / 2097152.0f);     // /128^3
        w *= (1.0f / 268435456.0f);   // /128^4
        y *= (1.0f / 268435456.0f);
        const float Wv = Wp[i], Yv = Yp[i];
        const float mmr   = C_SIGMA * (C_ALPHA * Yv);
        const float sig2  = C_SIGMA * C_SIGMA;
        const float coeff = -1.0f / (Wv * w + 1e-8f);
        const float myo   = coeff * (l * (mmr / sig2));
        const float hedge = coeff * (C_SIGMA * C_RHO * C_SIGY * y / sig2);
        float v = myo + hedge;
        v = fminf(fmaxf(v, -2.0f), 2.0f);
        out[i] = v;
    }
}

extern "C" void kernel_launch(void* const* d_in, const int* in_sizes, int n_in,
                              void* d_out, int out_size, void* d_ws, size_t ws_size,
                              hipStream_t stream) {
    const float* Wp    = (const float*)d_in[0];
    // d_in[1] = TmT (unused: reference simulates from T_H constant)
    const float* Yp    = (const float*)d_in[2];
    const float* noise = (const float*)d_in[3];
    const float* w1    = (const float*)d_in[4];
    const float* b1    = (const float*)d_in[5];
    const float* w2    = (const float*)d_in[6];
    const float* b2    = (const float*)d_in[7];
    const float* w3    = (const float*)d_in[8];
    const float* b3    = (const float*)d_in[9];
    float* out = (float*)d_out;
    float* sd  = (float*)d_ws;   // 3*8192 floats = 96 KB staging

    hipLaunchKernelGGL(sim_kernel, dim3(NBLK), dim3(256), 0, stream,
                       noise, w1, b1, w2, b2, w3, b3, Wp, Yp, sd);
    hipLaunchKernelGGL(proj_kernel, dim3(1), dim3(512), 0, stream, sd, Wp, Yp, out);
}

// Round 5
// 163.068 us; speedup vs baseline: 1.3860x; 1.0535x over previous
//
#include <hip/hip_runtime.h>
#include <math.h>

#define HID    64
#define MSTEPS 60
#define NPTS   32
#define RPTSC  128
#define BTOT   (RPTSC*NPTS)    // 4096 paths
#define NSIM   (2*BTOT)        // 8192 path-branches
#define NWAVE  (NSIM/2)        // 4096 waves, 2 path-branches per wave
#define NBLK   (NWAVE/4)       // 1024 blocks

// hard-coded model constants (match reference, fp32 semantics)
#define C_DT     0.025f
#define C_SQDT   0.15811388300841897f   // sqrt(0.025)
#define C_ALPHA  0.8f
#define C_RHO    0.3f
#define C_SQ1MR2 0.9539392014169456f    // sqrt(1-0.09)
#define C_KAPPA  1.2f
#define C_R      0.02f
#define C_SIGMA  0.2f
#define C_SIGY   0.3f
#define C_LBW    1e-3f
#define C_LOGLBW -6.907755279f          // log(1e-3)
#define C_2L2E   2.8853900817779268f    // 2*log2(e): tanh(x)=1-2/(2^(x*2L2E)+1)

// per-wave LDS layout:
//   [0,2304)      A-buffer: 16 rows x 144 B (64 f16 + 16 B pad)
//   [2304,3328)   DV: per unit u: [u*16 + p*8] int2 of f16 (a0,aW | aY,aWW)
//   [3328,3584)   DA: [p][tpair][mrow] dwords, dword = {aWY(t even), aWY(t odd)}
#define WAVE_LDS 3584
#define A_ROW    144
#define OFF_DV   2304
#define OFF_DA   3328

typedef _Float16 half8 __attribute__((ext_vector_type(8)));
typedef float    f32x4 __attribute__((ext_vector_type(4)));
typedef _Float16 h2    __attribute__((ext_vector_type(2)));

__device__ __forceinline__ float rlanef(float v, int l) {
    return __int_as_float(__builtin_amdgcn_readlane(__float_as_int(v), l));
}
__device__ __forceinline__ f32x4 MFMA(half8 a, half8 b, f32x4 c) {
    return __builtin_amdgcn_mfma_f32_16x16x32_f16(a, b, c, 0, 0, 0);
}
// pack two f32 -> f16x2 (RTZ) as int
__device__ __forceinline__ int pk16(float a, float b) {
    return __builtin_bit_cast(int, __builtin_amdgcn_cvt_pkrtz(a, b));
}
__device__ __forceinline__ h2 pk2(float a, float b) {
    return __builtin_bit_cast(h2, __builtin_amdgcn_cvt_pkrtz(a, b));
}
// v_perm_b32 byte gather: sel byte<4 picks from s1, >=4 picks from s0
__device__ __forceinline__ h2 permh(unsigned s0, unsigned s1, unsigned sel) {
    return __builtin_bit_cast(h2, __builtin_amdgcn_perm(s0, s1, sel));
}
// tanh with argument pre-scaled by 2*log2(e): tanh = 1 - 2/(2^xs + 1)
__device__ __forceinline__ float tanh_fast(float xs) {
    return 1.0f - 2.0f * __builtin_amdgcn_rcpf(__builtin_amdgcn_exp2f(xs) + 1.0f);
}

// sim: per-branch derivatives stored directly (no atomics, no zero-init).
// sd[c*NSIM + branch], branch = simb*BTOT + pg; branch & 31 == eval point.
__global__ __launch_bounds__(256, 4) void sim_kernel(
    const float* __restrict__ noise,
    const float* __restrict__ w1, const float* __restrict__ b1,
    const float* __restrict__ w2, const float* __restrict__ b2,
    const float* __restrict__ w3, const float* __restrict__ b3,
    const float* __restrict__ Wp, const float* __restrict__ Yp,
    float* __restrict__ sd)
{
    __shared__ __align__(16) char smem[4 * WAVE_LDS];
    const int lane = threadIdx.x & 63;
    const int quad = lane >> 4;      // 0..3
    const int mrow = lane & 15;      // 0..15
    const int par  = lane >> 5;      // path half: lanes 0-31 path0, 32-63 path1
    const bool phi = (par != 0);
    char* wb = smem + (threadIdx.x >> 6) * WAVE_LDS;

    const int w = __builtin_amdgcn_readfirstlane(
        (int)((blockIdx.x * blockDim.x + threadIdx.x) >> 6));   // 0..4095
    const int simb = w >> 11;                 // antithetic branch (uniform per wave)
    const int pg   = 2*(w & 2047) + par;      // per-lane global path 0..4095
    const int i    = pg & (NPTS - 1);         // per-lane eval point

    // per-lane layer-1 weights (lane = hidden unit)
    const float cW  = w1[lane];
    const float cT  = w1[HID + lane];
    const float cYw = w1[2*HID + lane];
    const float b1k = b1[lane];
    const float b2k = b2[lane];
    const float b3v = b3[0];
    // exp2-folded variants for tanh_fast
    const float cW_s  = cW  * C_2L2E;
    const float cT_s  = cT  * C_2L2E;
    const float cYw_s = cYw * C_2L2E;
    const float b1_s  = b1k * C_2L2E;
    const float b2_s  = b2k * C_2L2E;
    // packed-f16 jet constants (-2 folded into the ddp products)
    const h2 cWh  = pk2(cW, cW);
    const h2 cYwh = pk2(cYw, cYw);
    const h2 cW2m = pk2(-2.0f*cW*cW,  -2.0f*cW*cW);
    const h2 cWYm = pk2(-2.0f*cW*cYw, -2.0f*cW*cYw);
    const h2 hone = {(_Float16)1.0f,  (_Float16)1.0f};
    const h2 m2h  = {(_Float16)-2.0f, (_Float16)-2.0f};
    // DA extract selector: unit's tile parity picks low/high f16 of each dword
    const unsigned daSel = (quad & 1) ? 0x07060302u : 0x05040100u;

    // MFMA B fragments (f16): B[k][n], n=mrow+t*16, k=q*32+quad*8+j
    half8 B00, B01, B02, B03, B10, B11, B12, B13, W30, W31;
    {
        half8 h;
        #define LOADB(dst, q, t) \
            { for (int j = 0; j < 8; ++j) \
                h[j] = (_Float16)w2[((q)*32 + quad*8 + j)*HID + (t)*16 + mrow]; \
              dst = h; }
        LOADB(B00, 0, 0) LOADB(B01, 0, 1) LOADB(B02, 0, 2) LOADB(B03, 0, 3)
        LOADB(B10, 1, 0) LOADB(B11, 1, 1) LOADB(B12, 1, 2) LOADB(B13, 1, 3)
        #undef LOADB
        for (int j = 0; j < 8; ++j) h[j] = (_Float16)w3[0*32 + quad*8 + j];
        W30 = h;
        for (int j = 0; j < 8; ++j) h[j] = (_Float16)w3[1*32 + quad*8 + j];
        W31 = h;
    }

    // zero A-buffer once (rows 5-7, 13-15 must stay zero)
    for (int off = lane*4; off < 16*A_ROW; off += 256)
        *(float*)(wb + off) = 0.0f;

    // LDS addresses
    _Float16* swp = (_Float16*)(wb + lane*2);   // + row*72 elements
    char* arp0 = wb + mrow*A_ROW + quad*16;     // A-frag k-iter 0 (+64 B for iter 1)
    char* daw = wb + OFF_DA + ((quad >> 1) << 7) + (mrow << 2);   // writer (odd quads)
    char* dar = wb + OFF_DA + ((lane >> 5) << 6) + (mrow << 2);   // reader (unit=lane)

    // per-lane noise pointers (half-wave uniform)
    const float* zp1 = noise + (size_t)(simb*2 + 0) * MSTEPS * BTOT + pg;
    const float* zp2 = noise + (size_t)(simb*2 + 1) * MSTEPS * BTOT + pg;

    // ---- precomputed dynamics coefficients (fold anti & constants)
    const float anti = simb ? -1.0f : 1.0f;
    const float ksa  = C_SIGMA * C_ALPHA;
    const float ks2  = C_SIGMA * C_SIGMA;
    const float ksn  = anti * C_SIGMA * C_SQDT;
    const float kFy  = ksa * C_DT;
    const float ksd  = ks2 * C_DT;
    const float kv   = 0.5f * ks2 * C_DT;
    const float kRdt = C_R * C_DT;
    const float ky1  = anti * C_SIGY * C_SQDT * C_RHO;
    const float ky2  = anti * C_SIGY * C_SQDT * C_SQ1MR2;
    const float cYfac = 1.0f - C_KAPPA * C_DT;

    // per-lane path state + jets of L = logW
    const float W0 = Wp[i];
    float L   = __logf(fmaxf(W0, C_LBW));
    float W   = __expf(L);
    float Yv  = Yp[i];
    float tmt = 1.5f;
    float gW  = 1.0f / W0;
    float hWW = -gW * gW;
    float gY  = 0.0f, hWY = 0.0f;
    float cYt = 1.0f;

    // software-pipelined noise (issue next step's loads a full body ahead)
    float z1c = zp1[0];
    float z2c = zp2[0];

    #pragma unroll 1
    for (int m = 0; m < MSTEPS; ++m) {
        asm volatile("" : "+v"(B00), "+v"(B01), "+v"(B02), "+v"(B03),
                          "+v"(B10), "+v"(B11), "+v"(B12), "+v"(B13),
                          "+v"(W30), "+v"(W31));

        const float z1 = z1c, z2 = z2c;
        const int mn = (m + 1 < MSTEPS) ? m + 1 : m;
        z1c = zp1[(size_t)mn * BTOT];
        z2c = zp2[(size_t)mn * BTOT];

        // broadcast both paths' (W,Y): path0 state in lane 0, path1 in lane 32
        const float Wb0 = rlanef(W, 0),  Wb1 = rlanef(W, 32);
        const float Yb0 = rlanef(Yv, 0), Yb1 = rlanef(Yv, 32);

        // ---- layer 1 + tanh, both paths packed f16; marshal A rows 8p..8p+4
        const float base1s = fmaf(tmt, cT_s, b1_s);
        {
            const float t10 = tanh_fast(fmaf(Wb0, cW_s, fmaf(Yb0, cYw_s, base1s)));
            const float t11 = tanh_fast(fmaf(Wb1, cW_s, fmaf(Yb1, cYw_s, base1s)));
            const h2 tp  = pk2(t10, t11);
            const h2 dpp = hone - tp * tp;      // v_pk_fma
            const h2 ddq = tp * dpp;            // (-2) folded into cW2m/cWYm
            const h2 r1 = dpp * cWh;
            const h2 r2 = dpp * cYwh;
            const h2 r3 = ddq * cW2m;
            const h2 r4 = ddq * cWYm;
            swp[0*72] = tp.x;  swp[8*72]  = tp.y;   // hi halves -> ds_write_b16_d16_hi
            swp[1*72] = r1.x;  swp[9*72]  = r1.y;
            swp[2*72] = r2.x;  swp[10*72] = r2.y;
            swp[3*72] = r3.x;  swp[11*72] = r3.y;
            swp[4*72] = r4.x;  swp[12*72] = r4.y;
        }

        half8 af0 = __builtin_bit_cast(half8, *(const f32x4*)arp0);
        half8 af1 = __builtin_bit_cast(half8, *(const f32x4*)(arp0 + 64));

        // ---- layer 2 GEMM: 4 N-tiles x 2 K-iters
        f32x4 acc[4];
        const f32x4 zz = {0.f, 0.f, 0.f, 0.f};
        acc[0] = MFMA(af1, B10, MFMA(af0, B00, zz));
        acc[1] = MFMA(af1, B11, MFMA(af0, B01, zz));
        acc[2] = MFMA(af1, B12, MFMA(af0, B02, zz));
        acc[3] = MFMA(af1, B13, MFMA(af0, B03, zz));

        // ---- D transpose via LDS, packed f16
        // even quads: DV per unit [u*16 + p*8] int2 (a0,aW | aY,aWW)
        // odd quads:  DA [p][tpair][mrow]: dword = pk16(aWY[t even], aWY[t odd])
        //             -> 2 same-vaddr b32 stores (write2-eligible), no same-dword
        //             lane pairs (conflict fix vs 4x b16 scatter)
        {
            const int p = quad >> 1;
            if (!(quad & 1)) {
                #pragma unroll
                for (int t = 0; t < 4; ++t) {
                    int2 v;
                    v.x = pk16(acc[t].x, acc[t].y);
                    v.y = pk16(acc[t].z, acc[t].w);
                    *(int2*)(wb + OFF_DV + ((t*16 + mrow) << 4) + (p << 3)) = v;
                }
            } else {
                const int d0 = pk16(acc[0].x, acc[1].x);
                const int d1 = pk16(acc[2].x, acc[3].x);
                *(int*)daw        = d0;
                *(int*)(daw + 64) = d1;
            }
        }

        // ---- per-lane (unit k): one b128 + read2-eligible DA pair, v_perm repair
        const f32x4 dvv = *(const f32x4*)(wb + OFF_DV + lane*16);
        const int da_lo = *(const int*)dar;          // p0 {t even, t odd}
        const int da_hi = *(const int*)(dar + 128);  // p1 {t even, t odd}
        {
            const unsigned q0 = __builtin_bit_cast(unsigned, dvv.x); // p0 (a0,aW)
            const unsigned q1 = __builtin_bit_cast(unsigned, dvv.y); // p0 (aY,aWW)
            const unsigned q2 = __builtin_bit_cast(unsigned, dvv.z); // p1 (a0,aW)
            const unsigned q3 = __builtin_bit_cast(unsigned, dvv.w); // p1 (aY,aWW)
            const h2 a0p  = permh(q2, q0, 0x05040100);
            const h2 aWp  = permh(q2, q0, 0x07060302);
            const h2 aYp  = permh(q3, q1, 0x05040100);
            const h2 aWWp = permh(q3, q1, 0x07060302);
            const h2 awyp = permh((unsigned)da_hi, (unsigned)da_lo, daSel);

            const float t20 = tanh_fast(fmaf((float)a0p.x, C_2L2E, b2_s));
            const float t21 = tanh_fast(fmaf((float)a0p.y, C_2L2E, b2_s));
            const h2 t2p = pk2(t20, t21);
            const h2 d2p = hone - t2p * t2p;
            const h2 qp  = (m2h * (t2p * d2p)) * aWp;   // dd2 * aW
            const h2 s1 = d2p * aWp;
            const h2 s2 = d2p * aYp;
            const h2 s3 = qp * aWp + d2p * aWWp;
            const h2 s4 = qp * aYp + d2p * awyp;
            swp[0*72] = t2p.x; swp[8*72]  = t2p.y;
            swp[1*72] = s1.x;  swp[9*72]  = s1.y;
            swp[2*72] = s2.x;  swp[10*72] = s2.y;
            swp[3*72] = s3.x;  swp[11*72] = s3.y;
            swp[4*72] = s4.x;  swp[12*72] = s4.y;
        }

        // ---- layer 3 via MFMA (w3 broadcast over n -> all cols equal)
        half8 bf0 = __builtin_bit_cast(half8, *(const f32x4*)arp0);
        half8 bf1 = __builtin_bit_cast(half8, *(const f32x4*)(arp0 + 64));
        f32x4 acc4 = MFMA(bf1, W31, MFMA(bf0, W30, zz));

        // ---- policy-jet broadcast via v_readlane (VALU pipe, replaces 5
        // ds_swizzle on the saturated per-CU LDS pipe). Known locations:
        // p0: rows 0-3 in lane 0 regs x..w, row 4 in lane 16 reg x;
        // p1: lane 32 / lane 48.
        const float pi0  = rlanef(acc4.x,  0), pi1  = rlanef(acc4.x, 32);
        const float pW0  = rlanef(acc4.y,  0), pW1  = rlanef(acc4.y, 32);
        const float pY0  = rlanef(acc4.z,  0), pY1  = rlanef(acc4.z, 32);
        const float pWW0 = rlanef(acc4.w,  0), pWW1 = rlanef(acc4.w, 32);
        const float pWY0 = rlanef(acc4.x, 16), pWY1 = rlanef(acc4.x, 48);
        const float pi  = (phi ? pi1  : pi0) + b3v;
        const float pW  = phi ? pW1  : pW0;
        const float pY  = phi ? pY1  : pY0;
        const float pWW = phi ? pWW1 : pWW0;
        const float pWY = phi ? pWY1 : pWY0;

        // ---- dynamics + jet update (refactored: shared GdtSn factor)
        const float Sn    = ksn * z1;
        const float say   = ksa * Yv;
        const float G     = fmaf(-ks2, pi, say);
        const float GdtSn = fmaf(G, C_DT, Sn);

        const float w2v  = W * W;
        const float piL  = pW * W;
        const float piLL = fmaf(pWW, w2v, piL);
        const float piY  = pY;
        const float piLY = pWY * W;

        const float pi2  = pi * pi;
        const float Lnew = fmaf(pi, fmaf(say, C_DT, Sn),
                                fmaf(-kv, pi2, L + kRdt));

        const float F_L  = fmaf(piL, GdtSn, 1.0f);
        const float F_Y  = fmaf(piY, GdtSn, kFy * pi);
        const float piL2 = piL * piL;
        const float F_LL = fmaf(piLL, GdtSn, -(ksd * piL2));
        const float F_LY = fmaf(piLY, GdtSn, piL * fmaf(-ksd, piY, kFy));

        const float gW2  = gW * gW;
        const float hWWn = fmaf(F_LL, gW2, F_L * hWW);
        const float hWYn = fmaf(F_LL, gW * gY,
                                fmaf(F_LY, gW * cYt, F_L * hWY));
        const float gWn  = F_L * gW;
        const float gYn  = fmaf(F_Y, cYt, F_L * gY);

        Yv  = fmaf(ky2, z2, fmaf(ky1, z1, cYfac * Yv));
        cYt *= cYfac;

        const float We   = __expf(Lnew);
        const bool  clip = (We < C_LBW);
        L   = clip ? C_LOGLBW : Lnew;
        W   = clip ? C_LBW    : We;
        gW  = clip ? 0.0f : gWn;
        gY  = clip ? 0.0f : gYn;
        hWW = clip ? 0.0f : hWWn;
        hWY = clip ? 0.0f : hWYn;
        tmt -= C_DT;
    }

    // terminal utility U = -0.25*exp(-4L); direct per-branch store (no atomics)
    const float E   = __expf(-4.0f * L);
    const float d1  = E * gW;
    const float d2v = fmaf(-4.0f * E, gW * gW, E * hWW);
    const float d3v = fmaf(-4.0f * E, gW * gY, E * hWY);

    if ((lane & 31) == 0) {   // lane 0 = path 2w', lane 32 = path 2w'+1
        const int branch = simb * BTOT + pg;      // 0..8191, branch&31 == i
        sd[         branch] = 0.5f * d1;
        sd[  NSIM + branch] = 0.5f * d2v;
        sd[2*NSIM + branch] = 0.5f * d3v;
    }
}

// 512 threads: 16 chunk-accumulators per eval point, LDS tree reduce.
__global__ __launch_bounds__(512) void proj_kernel(
    const float* __restrict__ sd,
    const float* __restrict__ Wp,
    const float* __restrict__ Yp,
    float* __restrict__ out)
{
    __shared__ float red[3 * 512];
    const int tid = threadIdx.x;
    const int i = tid & 31;
    const int c = tid >> 5;           // 0..15
    float lam = 0.f, dW = 0.f, dY = 0.f;
    #pragma unroll 4
    for (int jj = 0; jj < 16; ++jj) {            // 256 chunks of 32 floats total
        const int idx = i + ((jj*16 + c) << 5);  // coalesced 128B per 32 lanes
        lam += sd[idx];
        dW  += sd[NSIM + idx];
        dY  += sd[2*NSIM + idx];
    }
    red[tid] = lam; red[512 + tid] = dW; red[1024 + tid] = dY;
    __syncthreads();
    if (tid < NPTS) {
        float l = 0.f, w = 0.f, y = 0.f;
        #pragma unroll
        for (int c2 = 0; c2 < 16; ++c2) {
            l += red[c2*32 + i];
            w += red[512 + c2*32 + i];
            y += red[1024 + c2*32 + i];
        }
        l *= (1.0f / 2097152.0f);     // /128^3
        w *= (1.0f / 268435456.0f);   // /128^4
        y *= (1.0f / 268435456.0f);
        const float Wv = Wp[i], Yv = Yp[i];
        const float mmr   = C_SIGMA * (C_ALPHA * Yv);
        const float sig2  = C_SIGMA * C_SIGMA;
        const float coeff = -1.0f / (Wv * w + 1e-8f);
        const float myo   = coeff * (l * (mmr / sig2));
        const float hedge = coeff * (C_SIGMA * C_RHO * C_SIGY * y / sig2);
        float v = myo + hedge;
        v = fminf(fmaxf(v, -2.0f), 2.0f);
        out[i] = v;
    }
}

extern "C" void kernel_launch(void* const* d_in, const int* in_sizes, int n_in,
                              void* d_out, int out_size, void* d_ws, size_t ws_size,
                              hipStream_t stream) {
    const float* Wp    = (const float*)d_in[0];
    // d_in[1] = TmT (unused: reference simulates from T_H constant)
    const float* Yp    = (const float*)d_in[2];
    const float* noise = (const float*)d_in[3];
    const float* w1    = (const float*)d_in[4];
    const float* b1    = (const float*)d_in[5];
    const float* w2    = (const float*)d_in[6];
    const float* b2    = (const float*)d_in[7];
    const float* w3    = (const float*)d_in[8];
    const float* b3    = (const float*)d_in[9];
    float* out = (float*)d_out;
    float* sd  = (float*)d_ws;   // 3*8192 floats = 96 KB staging

    hipLaunchKernelGGL(sim_kernel, dim3(NBLK), dim3(256), 0, stream,
                       noise, w1, b1, w2, b2, w3, b3, Wp, Yp, sd);
    hipLaunchKernelGGL(proj_kernel, dim3(1), dim3(512), 0, stream, sd, Wp, Yp, out);
}

// Round 6
// 161.117 us; speedup vs baseline: 1.4028x; 1.0121x over previous
//
#include <hip/hip_runtime.h>
#include <math.h>

#define HID    64
#define MSTEPS 60
#define NPTS   32
#define RPTSC  128
#define BTOT   (RPTSC*NPTS)    // 4096 paths
#define NSIM   (2*BTOT)        // 8192 path-branches
#define NWAVE  (NSIM/2)        // 4096 waves, 2 path-branches per wave
#define NBLK   (NWAVE/4)       // 1024 blocks

// hard-coded model constants (match reference, fp32 semantics)
#define C_DT     0.025f
#define C_SQDT   0.15811388300841897f   // sqrt(0.025)
#define C_ALPHA  0.8f
#define C_RHO    0.3f
#define C_SQ1MR2 0.9539392014169456f    // sqrt(1-0.09)
#define C_KAPPA  1.2f
#define C_R      0.02f
#define C_SIGMA  0.2f
#define C_SIGY   0.3f
#define C_LBW    1e-3f
#define C_LOGLBW -6.907755279f          // log(1e-3)
#define C_2L2E   2.8853900817779268f    // 2*log2(e): tanh(x)=1-2/(2^(x*2L2E)+1)

// per-wave LDS layout:
//   [0,2304)      A-buffer: 16 rows x 144 B (64 f16 + 16 B pad)
//   [2304,3328)   DV: per unit u: [u*16 + p*8] int2 of f16 (a0,aW | aY,aWW)
//   [3328,3584)   DA: [p][tpair][mrow] dwords, dword = {aWY(t even), aWY(t odd)}
#define WAVE_LDS 3584
#define A_ROW    144
#define OFF_DV   2304
#define OFF_DA   3328

typedef _Float16 half8 __attribute__((ext_vector_type(8)));
typedef float    f32x4 __attribute__((ext_vector_type(4)));
typedef _Float16 h2    __attribute__((ext_vector_type(2)));

__device__ __forceinline__ float rlanef(float v, int l) {
    return __int_as_float(__builtin_amdgcn_readlane(__float_as_int(v), l));
}
__device__ __forceinline__ f32x4 MFMA(half8 a, half8 b, f32x4 c) {
    return __builtin_amdgcn_mfma_f32_16x16x32_f16(a, b, c, 0, 0, 0);
}
// pack two f32 -> f16x2 (RTZ) as int
__device__ __forceinline__ int pk16(float a, float b) {
    return __builtin_bit_cast(int, __builtin_amdgcn_cvt_pkrtz(a, b));
}
__device__ __forceinline__ h2 pk2(float a, float b) {
    return __builtin_bit_cast(h2, __builtin_amdgcn_cvt_pkrtz(a, b));
}
// v_perm_b32 byte gather: sel byte<4 picks from s1, >=4 picks from s0
__device__ __forceinline__ h2 permh(unsigned s0, unsigned s1, unsigned sel) {
    return __builtin_bit_cast(h2, __builtin_amdgcn_perm(s0, s1, sel));
}
// tanh with argument pre-scaled by 2*log2(e): tanh = 1 - 2/(2^xs + 1)
__device__ __forceinline__ float tanh_fast(float xs) {
    return 1.0f - 2.0f * __builtin_amdgcn_rcpf(__builtin_amdgcn_exp2f(xs) + 1.0f);
}

// sim: per-branch derivatives stored directly (no atomics, no zero-init).
// sd[c*NSIM + branch], branch = simb*BTOT + pg; branch & 31 == eval point.
__global__ __launch_bounds__(256, 4) void sim_kernel(
    const float* __restrict__ noise,
    const float* __restrict__ w1, const float* __restrict__ b1,
    const float* __restrict__ w2, const float* __restrict__ b2,
    const float* __restrict__ w3, const float* __restrict__ b3,
    const float* __restrict__ Wp, const float* __restrict__ Yp,
    float* __restrict__ sd)
{
    // ---- anti-lockstep stagger: de-phase the ~4 co-resident blocks per CU
    // by 0/1/2/3 x 1024 cy so their step loops hit the LDS-turnaround and
    // VALU-dense phases at different times (collective-stall windows at
    // 1-pair/wave lockstep were ~20-25% of wall). ((bid>>8)+bid)&3 gives
    // distinct phases to co-residents under round-robin ({b, b+256, ...})
    // or chunked ({4c..4c+3}) dispatch. One-time cost <= 3072 cy.
    {
        const int ph = ((blockIdx.x >> 8) + blockIdx.x) & 3;
        if (ph > 0) __builtin_amdgcn_s_sleep(16);
        if (ph > 1) __builtin_amdgcn_s_sleep(16);
        if (ph > 2) __builtin_amdgcn_s_sleep(16);
    }

    __shared__ __align__(16) char smem[4 * WAVE_LDS];
    const int lane = threadIdx.x & 63;
    const int quad = lane >> 4;      // 0..3
    const int mrow = lane & 15;      // 0..15
    const int par  = lane >> 5;      // path half: lanes 0-31 path0, 32-63 path1
    const bool phi = (par != 0);
    char* wb = smem + (threadIdx.x >> 6) * WAVE_LDS;

    const int w = __builtin_amdgcn_readfirstlane(
        (int)((blockIdx.x * blockDim.x + threadIdx.x) >> 6));   // 0..4095
    const int simb = w >> 11;                 // antithetic branch (uniform per wave)
    const int pg   = 2*(w & 2047) + par;      // per-lane global path 0..4095
    const int i    = pg & (NPTS - 1);         // per-lane eval point

    // per-lane layer-1 weights (lane = hidden unit)
    const float cW  = w1[lane];
    const float cT  = w1[HID + lane];
    const float cYw = w1[2*HID + lane];
    const float b1k = b1[lane];
    const float b2k = b2[lane];
    const float b3v = b3[0];
    // exp2-folded variants for tanh_fast
    const float cW_s  = cW  * C_2L2E;
    const float cT_s  = cT  * C_2L2E;
    const float cYw_s = cYw * C_2L2E;
    const float b1_s  = b1k * C_2L2E;
    const float b2_s  = b2k * C_2L2E;
    // packed-f16 jet constants (-2 folded into the ddp products)
    const h2 cWh  = pk2(cW, cW);
    const h2 cYwh = pk2(cYw, cYw);
    const h2 cW2m = pk2(-2.0f*cW*cW,  -2.0f*cW*cW);
    const h2 cWYm = pk2(-2.0f*cW*cYw, -2.0f*cW*cYw);
    const h2 hone = {(_Float16)1.0f,  (_Float16)1.0f};
    const h2 m2h  = {(_Float16)-2.0f, (_Float16)-2.0f};
    // DA extract selector: unit's tile parity picks low/high f16 of each dword
    const unsigned daSel = (quad & 1) ? 0x07060302u : 0x05040100u;

    // MFMA B fragments (f16): B[k][n], n=mrow+t*16, k=q*32+quad*8+j
    half8 B00, B01, B02, B03, B10, B11, B12, B13, W30, W31;
    {
        half8 h;
        #define LOADB(dst, q, t) \
            { for (int j = 0; j < 8; ++j) \
                h[j] = (_Float16)w2[((q)*32 + quad*8 + j)*HID + (t)*16 + mrow]; \
              dst = h; }
        LOADB(B00, 0, 0) LOADB(B01, 0, 1) LOADB(B02, 0, 2) LOADB(B03, 0, 3)
        LOADB(B10, 1, 0) LOADB(B11, 1, 1) LOADB(B12, 1, 2) LOADB(B13, 1, 3)
        #undef LOADB
        for (int j = 0; j < 8; ++j) h[j] = (_Float16)w3[0*32 + quad*8 + j];
        W30 = h;
        for (int j = 0; j < 8; ++j) h[j] = (_Float16)w3[1*32 + quad*8 + j];
        W31 = h;
    }

    // zero A-buffer once (rows 5-7, 13-15 must stay zero)
    for (int off = lane*4; off < 16*A_ROW; off += 256)
        *(float*)(wb + off) = 0.0f;

    // LDS addresses
    _Float16* swp = (_Float16*)(wb + lane*2);   // + row*72 elements
    char* arp0 = wb + mrow*A_ROW + quad*16;     // A-frag k-iter 0 (+64 B for iter 1)
    char* daw = wb + OFF_DA + ((quad >> 1) << 7) + (mrow << 2);   // writer (odd quads)
    char* dar = wb + OFF_DA + ((lane >> 5) << 6) + (mrow << 2);   // reader (unit=lane)

    // per-lane noise pointers (half-wave uniform)
    const float* zp1 = noise + (size_t)(simb*2 + 0) * MSTEPS * BTOT + pg;
    const float* zp2 = noise + (size_t)(simb*2 + 1) * MSTEPS * BTOT + pg;

    // ---- precomputed dynamics coefficients (fold anti & constants)
    const float anti = simb ? -1.0f : 1.0f;
    const float ksa  = C_SIGMA * C_ALPHA;
    const float ks2  = C_SIGMA * C_SIGMA;
    const float ksn  = anti * C_SIGMA * C_SQDT;
    const float kFy  = ksa * C_DT;
    const float ksd  = ks2 * C_DT;
    const float kv   = 0.5f * ks2 * C_DT;
    const float kRdt = C_R * C_DT;
    const float ky1  = anti * C_SIGY * C_SQDT * C_RHO;
    const float ky2  = anti * C_SIGY * C_SQDT * C_SQ1MR2;
    const float cYfac = 1.0f - C_KAPPA * C_DT;

    // per-lane path state + jets of L = logW
    const float W0 = Wp[i];
    float L   = __logf(fmaxf(W0, C_LBW));
    float W   = __expf(L);
    float Yv  = Yp[i];
    float tmt = 1.5f;
    float gW  = 1.0f / W0;
    float hWW = -gW * gW;
    float gY  = 0.0f, hWY = 0.0f;
    float cYt = 1.0f;

    // software-pipelined noise (issue next step's loads a full body ahead)
    float z1c = zp1[0];
    float z2c = zp2[0];

    #pragma unroll 1
    for (int m = 0; m < MSTEPS; ++m) {
        asm volatile("" : "+v"(B00), "+v"(B01), "+v"(B02), "+v"(B03),
                          "+v"(B10), "+v"(B11), "+v"(B12), "+v"(B13),
                          "+v"(W30), "+v"(W31));

        const float z1 = z1c, z2 = z2c;
        const int mn = (m + 1 < MSTEPS) ? m + 1 : m;
        z1c = zp1[(size_t)mn * BTOT];
        z2c = zp2[(size_t)mn * BTOT];

        // broadcast both paths' (W,Y): path0 state in lane 0, path1 in lane 32
        const float Wb0 = rlanef(W, 0),  Wb1 = rlanef(W, 32);
        const float Yb0 = rlanef(Yv, 0), Yb1 = rlanef(Yv, 32);

        // ---- layer 1 + tanh, both paths packed f16; marshal A rows 8p..8p+4
        const float base1s = fmaf(tmt, cT_s, b1_s);
        {
            const float t10 = tanh_fast(fmaf(Wb0, cW_s, fmaf(Yb0, cYw_s, base1s)));
            const float t11 = tanh_fast(fmaf(Wb1, cW_s, fmaf(Yb1, cYw_s, base1s)));
            const h2 tp  = pk2(t10, t11);
            const h2 dpp = hone - tp * tp;      // v_pk_fma
            const h2 ddq = tp * dpp;            // (-2) folded into cW2m/cWYm
            const h2 r1 = dpp * cWh;
            const h2 r2 = dpp * cYwh;
            const h2 r3 = ddq * cW2m;
            const h2 r4 = ddq * cWYm;
            swp[0*72] = tp.x;  swp[8*72]  = tp.y;   // hi halves -> ds_write_b16_d16_hi
            swp[1*72] = r1.x;  swp[9*72]  = r1.y;
            swp[2*72] = r2.x;  swp[10*72] = r2.y;
            swp[3*72] = r3.x;  swp[11*72] = r3.y;
            swp[4*72] = r4.x;  swp[12*72] = r4.y;
        }

        half8 af0 = __builtin_bit_cast(half8, *(const f32x4*)arp0);
        half8 af1 = __builtin_bit_cast(half8, *(const f32x4*)(arp0 + 64));

        // ---- layer 2 GEMM: 4 N-tiles x 2 K-iters
        f32x4 acc[4];
        const f32x4 zz = {0.f, 0.f, 0.f, 0.f};
        acc[0] = MFMA(af1, B10, MFMA(af0, B00, zz));
        acc[1] = MFMA(af1, B11, MFMA(af0, B01, zz));
        acc[2] = MFMA(af1, B12, MFMA(af0, B02, zz));
        acc[3] = MFMA(af1, B13, MFMA(af0, B03, zz));

        // ---- D transpose via LDS, packed f16
        // even quads: DV per unit [u*16 + p*8] int2 (a0,aW | aY,aWW)
        // odd quads:  DA [p][tpair][mrow]: dword = pk16(aWY[t even], aWY[t odd])
        {
            const int p = quad >> 1;
            if (!(quad & 1)) {
                #pragma unroll
                for (int t = 0; t < 4; ++t) {
                    int2 v;
                    v.x = pk16(acc[t].x, acc[t].y);
                    v.y = pk16(acc[t].z, acc[t].w);
                    *(int2*)(wb + OFF_DV + ((t*16 + mrow) << 4) + (p << 3)) = v;
                }
            } else {
                const int d0 = pk16(acc[0].x, acc[1].x);
                const int d1 = pk16(acc[2].x, acc[3].x);
                *(int*)daw        = d0;
                *(int*)(daw + 64) = d1;
            }
        }

        // ---- per-lane (unit k): one b128 + read2-eligible DA pair, v_perm repair
        const f32x4 dvv = *(const f32x4*)(wb + OFF_DV + lane*16);
        const int da_lo = *(const int*)dar;          // p0 {t even, t odd}
        const int da_hi = *(const int*)(dar + 128);  // p1 {t even, t odd}
        {
            const unsigned q0 = __builtin_bit_cast(unsigned, dvv.x); // p0 (a0,aW)
            const unsigned q1 = __builtin_bit_cast(unsigned, dvv.y); // p0 (aY,aWW)
            const unsigned q2 = __builtin_bit_cast(unsigned, dvv.z); // p1 (a0,aW)
            const unsigned q3 = __builtin_bit_cast(unsigned, dvv.w); // p1 (aY,aWW)
            const h2 a0p  = permh(q2, q0, 0x05040100);
            const h2 aWp  = permh(q2, q0, 0x07060302);
            const h2 aYp  = permh(q3, q1, 0x05040100);
            const h2 aWWp = permh(q3, q1, 0x07060302);
            const h2 awyp = permh((unsigned)da_hi, (unsigned)da_lo, daSel);

            const float t20 = tanh_fast(fmaf((float)a0p.x, C_2L2E, b2_s));
            const float t21 = tanh_fast(fmaf((float)a0p.y, C_2L2E, b2_s));
            const h2 t2p = pk2(t20, t21);
            const h2 d2p = hone - t2p * t2p;
            const h2 qp  = (m2h * (t2p * d2p)) * aWp;   // dd2 * aW
            const h2 s1 = d2p * aWp;
            const h2 s2 = d2p * aYp;
            const h2 s3 = qp * aWp + d2p * aWWp;
            const h2 s4 = qp * aYp + d2p * awyp;
            swp[0*72] = t2p.x; swp[8*72]  = t2p.y;
            swp[1*72] = s1.x;  swp[9*72]  = s1.y;
            swp[2*72] = s2.x;  swp[10*72] = s2.y;
            swp[3*72] = s3.x;  swp[11*72] = s3.y;
            swp[4*72] = s4.x;  swp[12*72] = s4.y;
        }

        // ---- layer 3 via MFMA (w3 broadcast over n -> all cols equal)
        half8 bf0 = __builtin_bit_cast(half8, *(const f32x4*)arp0);
        half8 bf1 = __builtin_bit_cast(half8, *(const f32x4*)(arp0 + 64));
        f32x4 acc4 = MFMA(bf1, W31, MFMA(bf0, W30, zz));

        // ---- policy-jet broadcast via v_readlane (VALU pipe).
        // p0: rows 0-3 in lane 0 regs x..w, row 4 in lane 16 reg x;
        // p1: lane 32 / lane 48.
        const float pi0  = rlanef(acc4.x,  0), pi1  = rlanef(acc4.x, 32);
        const float pW0  = rlanef(acc4.y,  0), pW1  = rlanef(acc4.y, 32);
        const float pY0  = rlanef(acc4.z,  0), pY1  = rlanef(acc4.z, 32);
        const float pWW0 = rlanef(acc4.w,  0), pWW1 = rlanef(acc4.w, 32);
        const float pWY0 = rlanef(acc4.x, 16), pWY1 = rlanef(acc4.x, 48);
        const float pi  = (phi ? pi1  : pi0) + b3v;
        const float pW  = phi ? pW1  : pW0;
        const float pY  = phi ? pY1  : pY0;
        const float pWW = phi ? pWW1 : pWW0;
        const float pWY = phi ? pWY1 : pWY0;

        // ---- dynamics + jet update (refactored: shared GdtSn factor)
        const float Sn    = ksn * z1;
        const float say   = ksa * Yv;
        const float G     = fmaf(-ks2, pi, say);
        const float GdtSn = fmaf(G, C_DT, Sn);

        const float w2v  = W * W;
        const float piL  = pW * W;
        const float piLL = fmaf(pWW, w2v, piL);
        const float piY  = pY;
        const float piLY = pWY * W;

        const float pi2  = pi * pi;
        const float Lnew = fmaf(pi, fmaf(say, C_DT, Sn),
                                fmaf(-kv, pi2, L + kRdt));

        const float F_L  = fmaf(piL, GdtSn, 1.0f);
        const float F_Y  = fmaf(piY, GdtSn, kFy * pi);
        const float piL2 = piL * piL;
        const float F_LL = fmaf(piLL, GdtSn, -(ksd * piL2));
        const float F_LY = fmaf(piLY, GdtSn, piL * fmaf(-ksd, piY, kFy));

        const float gW2  = gW * gW;
        const float hWWn = fmaf(F_LL, gW2, F_L * hWW);
        const float hWYn = fmaf(F_LL, gW * gY,
                                fmaf(F_LY, gW * cYt, F_L * hWY));
        const float gWn  = F_L * gW;
        const float gYn  = fmaf(F_Y, cYt, F_L * gY);

        Yv  = fmaf(ky2, z2, fmaf(ky1, z1, cYfac * Yv));
        cYt *= cYfac;

        const float We   = __expf(Lnew);
        const bool  clip = (We < C_LBW);
        L   = clip ? C_LOGLBW : Lnew;
        W   = clip ? C_LBW    : We;
        gW  = clip ? 0.0f : gWn;
        gY  = clip ? 0.0f : gYn;
        hWW = clip ? 0.0f : hWWn;
        hWY = clip ? 0.0f : hWYn;
        tmt -= C_DT;
    }

    // terminal utility U = -0.25*exp(-4L); direct per-branch store (no atomics)
    const float E   = __expf(-4.0f * L);
    const float d1  = E * gW;
    const float d2v = fmaf(-4.0f * E, gW * gW, E * hWW);
    const float d3v = fmaf(-4.0f * E, gW * gY, E * hWY);

    if ((lane & 31) == 0) {   // lane 0 = path 2w', lane 32 = path 2w'+1
        const int branch = simb * BTOT + pg;      // 0..8191, branch&31 == i
        sd[         branch] = 0.5f * d1;
        sd[  NSIM + branch] = 0.5f * d2v;
        sd[2*NSIM + branch] = 0.5f * d3v;
    }
}

// 512 threads: 16 chunk-accumulators per eval point, LDS tree reduce.
__global__ __launch_bounds__(512) void proj_kernel(
    const float* __restrict__ sd,
    const float* __restrict__ Wp,
    const float* __restrict__ Yp,
    float* __restrict__ out)
{
    __shared__ float red[3 * 512];
    const int tid = threadIdx.x;
    const int i = tid & 31;
    const int c = tid >> 5;           // 0..15
    float lam = 0.f, dW = 0.f, dY = 0.f;
    #pragma unroll 4
    for (int jj = 0; jj < 16; ++jj) {            // 256 chunks of 32 floats total
        const int idx = i + ((jj*16 + c) << 5);  // coalesced 128B per 32 lanes
        lam += sd[idx];
        dW  += sd[NSIM + idx];
        dY  += sd[2*NSIM + idx];
    }
    red[tid] = lam; red[512 + tid] = dW; red[1024 + tid] = dY;
    __syncthreads();
    if (tid < NPTS) {
        float l = 0.f, w = 0.f, y = 0.f;
        #pragma unroll
        for (int c2 = 0; c2 < 16; ++c2) {
            l += red[c2*32 + i];
            w += red[512 + c2*32 + i];
            y += red[1024 + c2*32 + i];
        }
        l *= (1.0f / 2097152.0f);     // /128^3
        w *= (1.0f / 268435456.0f);   // /128^4
        y *= (1.0f / 268435456.0f);
        const float Wv = Wp[i], Yv = Yp[i];
        const float mmr   = C_SIGMA * (C_ALPHA * Yv);
        const float sig2  = C_SIGMA * C_SIGMA;
        const float coeff = -1.0f / (Wv * w + 1e-8f);
        const float myo   = coeff * (l * (mmr / sig2));
        const float hedge = coeff * (C_SIGMA * C_RHO * C_SIGY * y / sig2);
        float v = myo + hedge;
        v = fminf(fmaxf(v, -2.0f), 2.0f);
        out[i] = v;
    }
}

extern "C" void kernel_launch(void* const* d_in, const int* in_sizes, int n_in,
                              void* d_out, int out_size, void* d_ws, size_t ws_size,
                              hipStream_t stream) {
    const float* Wp    = (const float*)d_in[0];
    // d_in[1] = TmT (unused: reference simulates from T_H constant)
    const float* Yp    = (const float*)d_in[2];
    const float* noise = (const float*)d_in[3];
    const float* w1    = (const float*)d_in[4];
    const float* b1    = (const float*)d_in[5];
    const float* w2    = (const float*)d_in[6];
    const float* b2    = (const float*)d_in[7];
    const float* w3    = (const float*)d_in[8];
    const float* b3    = (const float*)d_in[9];
    float* out = (float*)d_out;
    float* sd  = (float*)d_ws;   // 3*8192 floats = 96 KB staging

    hipLaunchKernelGGL(sim_kernel, dim3(NBLK), dim3(256), 0, stream,
                       noise, w1, b1, w2, b2, w3, b3, Wp, Yp, sd);
    hipLaunchKernelGGL(proj_kernel, dim3(1), dim3(512), 0, stream, sd, Wp, Yp, out);
}